// Round 15
// baseline (280.806 us; speedup 1.0000x reference)
//
#include <hip/hip_runtime.h>
#include <hip/hip_fp16.h>

#define OUT_DIM 128
#define NPB 64               // nodes per bin == gather-block granularity
#define NB_MAX 1600          // bins per matrix (1563 actual)
#define CAP_B 1280           // slots per bin (mean 1024 + 8 sigma)
#define CURSTR 32            // cur[] stride in ints (1 cursor / 128-B line)
#define SBLK1 1024           // 16 waves/block
#define EPT1 4
#define CHUNK1 (SBLK1 * EPT1)   // 4096
#define FBLK 1024            // fused gather block: 64 groups x 16 lanes

// ---------- scatter1 body: chunk-local counting sort into 64-node bins ----------
// R11 lesson: LDS staging keeps payload writes line-coalesced. Bins now match
// gather blocks exactly, so sort2 (and its ~51 MB payload round-trip) is gone.
__device__ __forceinline__ void scatter1_body(
    const int* __restrict__ rows, const int* __restrict__ cols,
    const float* __restrict__ vals, int nnz, int chunk,
    int* __restrict__ cur, int2* __restrict__ pay, int nb, int matbase)
{
    __shared__ int2 s_stage[CHUNK1];            // 32 KB
    __shared__ unsigned short s_bin[CHUNK1];    // 8 KB
    __shared__ int s_hist[NB_MAX];              // 6.4 KB
    __shared__ int s_excl[NB_MAX];              // 6.4 KB
    __shared__ int s_gbase[NB_MAX];             // 6.4 KB  (59.2 KB -> 2 blk/CU)

    int tid = threadIdx.x;
    int start = chunk * CHUNK1;
    int total = nnz - start; if (total > CHUNK1) total = CHUNK1;

    for (int i = tid; i < nb; i += SBLK1) s_hist[i] = 0;
    __syncthreads();

    int rr[EPT1]; int cc[EPT1]; float vv[EPT1];
    #pragma unroll
    for (int k = 0; k < EPT1; ++k) {
        int e = start + k * SBLK1 + tid;
        rr[k] = -1;
        if (e < nnz) {
            rr[k] = rows[e]; cc[k] = cols[e]; vv[k] = vals[e];
            atomicAdd(&s_hist[rr[k] >> 6], 1);
        }
    }
    __syncthreads();

    // wave 0: exclusive scan of s_hist[0..nb) -> s_excl
    if (tid < 64) {
        int carry = 0;
        for (int seg = 0; seg < nb; seg += 64) {
            int idx = seg + tid;
            int x = (idx < nb) ? s_hist[idx] : 0;
            int incl = x;
            #pragma unroll
            for (int off = 1; off < 64; off <<= 1) {
                int y = __shfl_up(incl, off, 64);
                if (tid >= off) incl += y;
            }
            if (idx < nb) s_excl[idx] = carry + incl - x;
            carry += __shfl(incl, 63, 64);
        }
    }
    __syncthreads();

    // reserve global runs (one atomic per non-empty bin)
    for (int i = tid; i < nb; i += SBLK1) {
        int c = s_hist[i];
        s_gbase[i] = (c > 0) ? atomicAdd(&cur[(matbase + i) * CURSTR], c) : 0;
        s_hist[i] = 0;   // reuse as rank cursor
    }
    __syncthreads();

    // scatter into bin-sorted LDS staging (rl = row & 63, 6 bits)
    #pragma unroll
    for (int k = 0; k < EPT1; ++k) {
        if (rr[k] >= 0) {
            int b = rr[k] >> 6;
            int rl = rr[k] & 63;
            int pos = s_excl[b] + atomicAdd(&s_hist[b], 1);
            s_stage[pos] = make_int2((rl << 17) | cc[k], __float_as_int(vv[k]));
            s_bin[pos] = (unsigned short)b;
        }
    }
    __syncthreads();

    // coalesced write-out: consecutive threads -> consecutive slots of a run
    for (int i = tid; i < total; i += SBLK1) {
        int b = s_bin[i];
        int g = s_gbase[b] + (i - s_excl[b]);
        if (g < CAP_B)
            pay[(size_t)(matbase + b) * CAP_B + g] = s_stage[i];
    }
}

// ---------- stage 1: scatter X chunks only ----------
__global__ __launch_bounds__(SBLK1) void scatter1x_kernel(
    const int* __restrict__ rows, const int* __restrict__ cols,
    const float* __restrict__ vals, int nnz,
    int* __restrict__ cur, int2* __restrict__ pay, int nb)
{
    scatter1_body(rows, cols, vals, nnz, blockIdx.x, cur, pay, nb, nb);
}

// ---------- cast W to fp16 ----------
__global__ void wcast_kernel(const float* __restrict__ W, __half* __restrict__ W16, int n) {
    int i = blockIdx.x * blockDim.x + threadIdx.x;
    if (i < n) W16[i] = __float2half(W[i]);
}

// ---------- fused gather body: in-LDS bin sort (tiny) + frozen w[16] loop ----------
// R4 failure causes fixed: bin==block (single read), 10.8 KB LDS (wave-limited
// 32 waves/CU), 64-wide scan, <=2 staged regs. Sort prologue ~1280 entries.
template <bool IS_XW>
__device__ __forceinline__ void fused_gather_body(
    const int* __restrict__ cur, const int2* __restrict__ pay,
    const __half* __restrict__ table,       // XW (agg) or W16 (xw)
    __half* __restrict__ XW, float* __restrict__ out,
    int b, int nb, int n_nodes)
{
    __shared__ int2 s_edge[CAP_B];          // 10.2 KB
    __shared__ int s_cnt[NPB];
    __shared__ int s_excl[NPB];
    int tid = threadIdx.x;
    int matbase = IS_XW ? nb : 0;
    int count = cur[(matbase + b) * CURSTR]; if (count > CAP_B) count = CAP_B;
    const int2* region = pay + (size_t)(matbase + b) * CAP_B;

    if (tid < NPB) s_cnt[tid] = 0;
    __syncthreads();

    int2 e0 = make_int2(-1, 0), e1 = make_int2(-1, 0);
    if (tid < count) {
        e0 = region[tid];
        atomicAdd(&s_cnt[((unsigned)e0.x) >> 17], 1);
    }
    if (tid + FBLK < count) {
        e1 = region[tid + FBLK];
        atomicAdd(&s_cnt[((unsigned)e1.x) >> 17], 1);
    }
    __syncthreads();

    if (tid < 64) {                          // exclusive scan of 64 counters
        int x = s_cnt[tid];
        int incl = x;
        #pragma unroll
        for (int off = 1; off < 64; off <<= 1) {
            int y = __shfl_up(incl, off, 64);
            if (tid >= off) incl += y;
        }
        s_excl[tid] = incl - x;
    }
    __syncthreads();

    if (e0.x >= 0) {
        int rl = ((unsigned)e0.x) >> 17;
        int pos = atomicAdd(&s_excl[rl], 1);
        if (pos < CAP_B) s_edge[pos] = e0;
    }
    if (e1.x >= 0) {
        int rl = ((unsigned)e1.x) >> 17;
        int pos = atomicAdd(&s_excl[rl], 1);
        if (pos < CAP_B) s_edge[pos] = e1;
    }
    __syncthreads();

    // gather: group per node, frozen inner loop sourced from LDS
    int lane = tid & 15;
    int grp = tid >> 4;                      // 0..63
    int node = b * NPB + grp;
    if (node >= n_nodes) return;
    int cnt = s_cnt[grp];
    int gstart = s_excl[grp] - cnt;          // post-scatter cursor = end
    const int4* Tv = (const int4*)table;
    float a0=0,a1=0,a2=0,a3=0,a4=0,a5=0,a6=0,a7=0;
    for (int base = 0; base < cnt; base += 16) {
        int2 pl = make_int2(0, 0);
        if (base + lane < cnt) pl = s_edge[gstart + base + lane];
        int4 w[16];
        #pragma unroll
        for (int j = 0; j < 16; ++j) {
            int c = __shfl(pl.x, j, 16) & 0x1FFFF;  // pad lanes: c=0 (hot row)
            w[j] = Tv[(size_t)((c << 4) | lane)];
        }
        #pragma unroll
        for (int j = 0; j < 16; ++j) {
            float v = __int_as_float(__shfl(pl.y, j, 16));  // pad lanes: v=0
            union { int4 i4; __half2 h[4]; } u;
            u.i4 = w[j];
            float2 f0 = __half22float2(u.h[0]);
            float2 f1 = __half22float2(u.h[1]);
            float2 f2 = __half22float2(u.h[2]);
            float2 f3 = __half22float2(u.h[3]);
            a0 += v * f0.x; a1 += v * f0.y; a2 += v * f1.x; a3 += v * f1.y;
            a4 += v * f2.x; a5 += v * f2.y; a6 += v * f3.x; a7 += v * f3.y;
        }
    }
    if (IS_XW) {
        union { int4 i4; __half2 h[4]; } o;
        o.h[0] = __floats2half2_rn(a0, a1);
        o.h[1] = __floats2half2_rn(a2, a3);
        o.h[2] = __floats2half2_rn(a4, a5);
        o.h[3] = __floats2half2_rn(a6, a7);
        ((int4*)(XW + (size_t)node * OUT_DIM))[lane] = o.i4;
    } else {
        float4 lo, hi;
        lo.x = fmaxf(a0, 0.f); lo.y = fmaxf(a1, 0.f);
        lo.z = fmaxf(a2, 0.f); lo.w = fmaxf(a3, 0.f);
        hi.x = fmaxf(a4, 0.f); hi.y = fmaxf(a5, 0.f);
        hi.z = fmaxf(a6, 0.f); hi.w = fmaxf(a7, 0.f);
        float4* orow = (float4*)(out + (size_t)node * OUT_DIM);
        orow[2 * lane]     = lo;
        orow[2 * lane + 1] = hi;
    }
}

// ---------- stage 2: scatter1A (blocks [0,nCkA)) || fused_xw (rest) ----------
// Disjoint data: A-chunks write pay-A/cur-A; fused_xw reads cur-X/pay-X
// (complete after stage 1) + W16, writes XW.
__global__ __launch_bounds__(SBLK1) void scA_fxw_kernel(
    const int* __restrict__ adj_rows, const int* __restrict__ adj_cols,
    const float* __restrict__ adj_vals, int nnz_a, int nCkA,
    int* __restrict__ cur, int2* __restrict__ pay,
    const __half* __restrict__ W16, __half* __restrict__ XW,
    int nb, int n_nodes)
{
    if ((int)blockIdx.x < nCkA) {
        scatter1_body(adj_rows, adj_cols, adj_vals, nnz_a, blockIdx.x,
                      cur, pay, nb, 0);
    } else {
        fused_gather_body<true>(cur, pay, W16, XW, nullptr,
                                (int)blockIdx.x - nCkA, nb, n_nodes);
    }
}

// ---------- stage 3: fused agg (bin sort + gather + relu) ----------
__global__ __launch_bounds__(FBLK) void fused_agg_kernel(
    const int* __restrict__ cur, const int2* __restrict__ pay,
    const __half* __restrict__ XW, float* __restrict__ out,
    int nb, int n_nodes)
{
    fused_gather_body<false>(cur, pay, XW, nullptr, out,
                             blockIdx.x, nb, n_nodes);
}

extern "C" void kernel_launch(void* const* d_in, const int* in_sizes, int n_in,
                              void* d_out, int out_size, void* d_ws, size_t ws_size,
                              hipStream_t stream) {
    const int*   feat_rows = (const int*)d_in[0];
    const int*   feat_cols = (const int*)d_in[1];
    const float* feat_vals = (const float*)d_in[2];
    const int*   adj_rows  = (const int*)d_in[3];
    const int*   adj_cols  = (const int*)d_in[4];
    const float* adj_vals  = (const float*)d_in[5];
    const float* W         = (const float*)d_in[6];
    float*       out       = (float*)d_out;

    const int nnz_x   = in_sizes[0];
    const int nnz_a   = in_sizes[3];
    const int n_w     = in_sizes[6];          // 256*128
    const int n_nodes = out_size / OUT_DIM;
    const int nb      = (n_nodes + NPB - 1) / NPB;   // 1563 bins per matrix

    // ---- workspace layout (~58 MB) ----
    char* p = (char*)d_ws;
    __half* XW   = (__half*)p;  p += (size_t)n_nodes * OUT_DIM * sizeof(__half); // 25.6 MB
    __half* W16  = (__half*)p;  p += (size_t)n_w * sizeof(__half);               // 64 KB
    p = (char*)(((uintptr_t)p + 127) & ~(uintptr_t)127);
    int2* pay    = (int2*)p;    p += (size_t)2 * nb * CAP_B * sizeof(int2);      // 32.0 MB
    p = (char*)(((uintptr_t)p + 127) & ~(uintptr_t)127);
    int* cur     = (int*)p;     p += (size_t)2 * nb * CURSTR * sizeof(int);      // 400 KB

    (void)hipMemsetAsync(cur, 0, (size_t)2 * nb * CURSTR * sizeof(int), stream);

    wcast_kernel<<<(n_w + 255) / 256, 256, 0, stream>>>(W, W16, n_w);

    const int nCkA = (nnz_a + CHUNK1 - 1) / CHUNK1;
    const int nCkX = (nnz_x + CHUNK1 - 1) / CHUNK1;

    // stage 1: X chunks -> 64-node bins
    scatter1x_kernel<<<nCkX, SBLK1, 0, stream>>>(
        feat_rows, feat_cols, feat_vals, nnz_x, cur, pay, nb);

    // stage 2: scatter1A || fused_xw (independent halves)
    scA_fxw_kernel<<<nCkA + nb, SBLK1, 0, stream>>>(
        adj_rows, adj_cols, adj_vals, nnz_a, nCkA,
        cur, pay, W16, XW, nb, n_nodes);

    // stage 3: fused agg
    fused_agg_kernel<<<nb, FBLK, 0, stream>>>(cur, pay, XW, out, nb, n_nodes);
}

// Round 16
// 234.677 us; speedup vs baseline: 1.1966x; 1.1966x over previous
//
#include <hip/hip_runtime.h>
#include <hip/hip_fp16.h>

#define OUT_DIM 128
#define NPS 256              // nodes per super-bucket
#define NS_MAX 400           // supers per matrix (391 actual)
#define CAP_S 4608           // payload slots per super (mean 4096 + 8 sigma)
#define CURSTR 32            // cur[] stride in ints (1 cursor / 128-B line)
#define SBLK1 1024           // 16 waves/block
#define EPT1 4
#define CHUNK1 (SBLK1 * EPT1)   // 4096
#define SBLK2 1024
#define EPT2 5               // ceil(CAP_S / SBLK2)
#define GBLK 256

// ---------- pass 1: chunk-local counting sort + coalesced run write-out ----------
// R13 structure (best measured, 234.4 us) + ONE change: edge loads vectorized.
// Each thread owns 4 CONSECUTIVE edges -> rows/cols/vals read as int4/float4
// (3 vector loads vs 12 scalar). R11 lesson retained: LDS staging keeps the
// payload write-out line-coalesced (scattered 8B stores cost 8x write-back).
__global__ __launch_bounds__(SBLK1) void scatter1_kernel(
    const int* __restrict__ adj_rows, const int* __restrict__ adj_cols,
    const float* __restrict__ adj_vals, int nnz_a, int nCkA,
    const int* __restrict__ feat_rows, const int* __restrict__ feat_cols,
    const float* __restrict__ feat_vals, int nnz_x,
    int* __restrict__ cur, int2* __restrict__ pay, int ns)
{
    __shared__ int2 s_stage[CHUNK1];            // 32 KB
    __shared__ unsigned short s_bin[CHUNK1];    // 8 KB
    __shared__ int s_hist[NS_MAX];
    __shared__ int s_excl[NS_MAX];
    __shared__ int s_gbase[NS_MAX];

    int tid = threadIdx.x;
    bool isA = ((int)blockIdx.x < nCkA);
    const int* rows; const int* cols; const float* vals;
    int nnz, start, matbase;
    if (isA) {
        rows = adj_rows; cols = adj_cols; vals = adj_vals; nnz = nnz_a;
        start = (int)blockIdx.x * CHUNK1; matbase = 0;
    } else {
        rows = feat_rows; cols = feat_cols; vals = feat_vals; nnz = nnz_x;
        start = ((int)blockIdx.x - nCkA) * CHUNK1; matbase = ns;
    }
    int total = nnz - start; if (total > CHUNK1) total = CHUNK1;

    for (int i = tid; i < ns; i += SBLK1) s_hist[i] = 0;
    __syncthreads();

    // vectorized edge staging: thread owns edges [start+4*tid, +4)
    int rr[EPT1]; int cc[EPT1]; float vv[EPT1];
    int e0 = start + tid * EPT1;
    if (e0 + EPT1 <= nnz) {                     // full quad: 3 x 16B loads
        int4   r4 = *(const int4*)(rows + e0);
        int4   c4 = *(const int4*)(cols + e0);
        float4 v4 = *(const float4*)(vals + e0);
        rr[0] = r4.x; rr[1] = r4.y; rr[2] = r4.z; rr[3] = r4.w;
        cc[0] = c4.x; cc[1] = c4.y; cc[2] = c4.z; cc[3] = c4.w;
        vv[0] = v4.x; vv[1] = v4.y; vv[2] = v4.z; vv[3] = v4.w;
        #pragma unroll
        for (int k = 0; k < EPT1; ++k)
            atomicAdd(&s_hist[rr[k] >> 8], 1);
    } else {                                    // tail chunk: scalar guarded
        #pragma unroll
        for (int k = 0; k < EPT1; ++k) {
            int e = e0 + k;
            rr[k] = -1;
            if (e < nnz) {
                rr[k] = rows[e]; cc[k] = cols[e]; vv[k] = vals[e];
                atomicAdd(&s_hist[rr[k] >> 8], 1);
            }
        }
    }
    __syncthreads();

    // wave 0: exclusive scan of s_hist[0..ns) -> s_excl
    if (tid < 64) {
        int carry = 0;
        for (int seg = 0; seg < ns; seg += 64) {
            int idx = seg + tid;
            int x = (idx < ns) ? s_hist[idx] : 0;
            int incl = x;
            #pragma unroll
            for (int off = 1; off < 64; off <<= 1) {
                int y = __shfl_up(incl, off, 64);
                if (tid >= off) incl += y;
            }
            if (idx < ns) s_excl[idx] = carry + incl - x;
            carry += __shfl(incl, 63, 64);
        }
    }
    __syncthreads();

    // reserve global runs (one atomic per non-empty super; 1 cursor/line)
    for (int i = tid; i < ns; i += SBLK1) {
        int c = s_hist[i];
        s_gbase[i] = (c > 0) ? atomicAdd(&cur[(matbase + i) * CURSTR], c) : 0;
        s_hist[i] = 0;   // reuse as rank cursor
    }
    __syncthreads();

    // scatter into sorted LDS staging
    #pragma unroll
    for (int k = 0; k < EPT1; ++k) {
        if (rr[k] >= 0) {
            int b = rr[k] >> 8;
            int rl = rr[k] & 255;
            int pos = s_excl[b] + atomicAdd(&s_hist[b], 1);
            s_stage[pos] = make_int2((rl << 17) | cc[k], __float_as_int(vv[k]));
            s_bin[pos] = (unsigned short)b;
        }
    }
    __syncthreads();

    // coalesced write-out: consecutive threads -> consecutive slots of a run
    for (int i = tid; i < total; i += SBLK1) {
        int b = s_bin[i];
        int g = s_gbase[b] + (i - s_excl[b]);
        if (g < CAP_S)
            pay[(size_t)(matbase + b) * CAP_S + g] = s_stage[i];
    }
}

// ---------- sort2 body (1024 threads): node-sort one super + per-node spans ----------
__device__ __forceinline__ void sort2_body(
    const int* __restrict__ cur, int2* __restrict__ pay,
    int2* __restrict__ row_span, int b, int ns, int n_nodes)
{
    __shared__ int s_cnt[NPS];
    __shared__ int s_excl[NPS];
    int tid = threadIdx.x;
    int count = cur[b * CURSTR]; if (count > CAP_S) count = CAP_S;
    int2* region = pay + (size_t)b * CAP_S;

    if (tid < NPS) s_cnt[tid] = 0;
    __syncthreads();

    int2 er[EPT2];
    #pragma unroll
    for (int k = 0; k < EPT2; ++k) {
        int i = tid + k * SBLK2;
        er[k] = make_int2(-1, 0);
        if (i < count) {
            er[k] = region[i];
            atomicAdd(&s_cnt[((unsigned)er[k].x) >> 17], 1);
        }
    }
    __syncthreads();

    if (tid < 64) {
        int carry = 0;
        #pragma unroll
        for (int seg = 0; seg < NPS; seg += 64) {
            int x = s_cnt[seg + tid];
            int incl = x;
            #pragma unroll
            for (int off = 1; off < 64; off <<= 1) {
                int y = __shfl_up(incl, off, 64);
                if (tid >= off) incl += y;
            }
            s_excl[seg + tid] = carry + incl - x;
            carry += __shfl(incl, 63, 64);
        }
    }
    __syncthreads();

    int m = (b >= ns) ? 1 : 0;
    if (tid < NPS) {
        int g = (b - m * ns) * NPS + tid;
        if (g < n_nodes)
            row_span[(size_t)m * n_nodes + g] =
                make_int2(b * CAP_S + s_excl[tid], s_cnt[tid]);
    }
    __syncthreads();

    #pragma unroll
    for (int k = 0; k < EPT2; ++k) {
        if (er[k].x >= 0) {
            int rl = ((unsigned)er[k].x) >> 17;
            int pos = atomicAdd(&s_excl[rl], 1);
            region[pos] = make_int2(er[k].x & 0x1FFFF, er[k].y);
        }
    }
}

// ---------- sort2 X-half (gather_xw depends on these spans) ----------
__global__ __launch_bounds__(SBLK2) void sort2x_kernel(
    const int* __restrict__ cur, int2* __restrict__ pay,
    int2* __restrict__ row_span, int ns, int n_nodes)
{
    sort2_body(cur, pay, row_span, ns + blockIdx.x, ns, n_nodes);
}

// ---------- cast W to fp16 ----------
__global__ void wcast_kernel(const float* __restrict__ W, __half* __restrict__ W16, int n) {
    int i = blockIdx.x * blockDim.x + threadIdx.x;
    if (i < n) W16[i] = __float2half(W[i]);
}

// ---------- merged: sort2 A-half (blocks [0,ns)) || gather_xw (rest) ----------
__global__ __launch_bounds__(SBLK2) void sortA_xw_kernel(
    const int* __restrict__ cur, int2* __restrict__ pay,
    int2* __restrict__ row_span,
    const __half* __restrict__ W16, __half* __restrict__ XW,
    int ns, int n_nodes)
{
    if ((int)blockIdx.x < ns) {
        sort2_body(cur, pay, row_span, blockIdx.x, ns, n_nodes);
        return;
    }
    // ---- gather_xw (R1 proven form: W16 int4 row fragments, shallow loop) ----
    int tid = threadIdx.x;
    int lane = tid & 15;
    int node = ((int)blockIdx.x - ns) * 64 + (tid >> 4);
    if (node >= n_nodes) return;
    int2 span = row_span[(size_t)n_nodes + node];   // X spans
    int s = span.x, cnt = span.y;
    const int4* Wv = (const int4*)W16;              // row = 16 int4 (8 halves)
    float a0=0,a1=0,a2=0,a3=0,a4=0,a5=0,a6=0,a7=0;
    for (int base = 0; base < cnt; base += 16) {
        int mm = cnt - base; if (mm > 16) mm = 16;
        int2 pl = make_int2(0, 0);
        if (lane < mm) pl = pay[s + base + lane];
        #pragma unroll 4
        for (int j = 0; j < mm; ++j) {
            int c = __shfl(pl.x, j, 16);
            float v = __int_as_float(__shfl(pl.y, j, 16));
            union { int4 i4; __half2 h[4]; } u;
            u.i4 = Wv[(size_t)c * 16 + lane];
            float2 f0 = __half22float2(u.h[0]);
            float2 f1 = __half22float2(u.h[1]);
            float2 f2 = __half22float2(u.h[2]);
            float2 f3 = __half22float2(u.h[3]);
            a0 += v * f0.x; a1 += v * f0.y; a2 += v * f1.x; a3 += v * f1.y;
            a4 += v * f2.x; a5 += v * f2.y; a6 += v * f3.x; a7 += v * f3.y;
        }
    }
    union { int4 i4; __half2 h[4]; } o;
    o.h[0] = __floats2half2_rn(a0, a1);
    o.h[1] = __floats2half2_rn(a2, a3);
    o.h[2] = __floats2half2_rn(a4, a5);
    o.h[3] = __floats2half2_rn(a6, a7);
    ((int4*)(XW + (size_t)node * OUT_DIM))[lane] = o.i4;
}

// ---------- stage 2: out[node,:] = relu( sum val * XW[col,:] ) ----------
// FROZEN (round-2 form, best measured 60.0 us): do not touch.
__global__ __launch_bounds__(GBLK, 4) void gather_agg_kernel(
    const int2* __restrict__ row_span, const int2* __restrict__ pay,
    const __half* __restrict__ XW, float* __restrict__ out, int n_nodes)
{
    int tid = threadIdx.x;
    int lane = tid & 15;
    int node = blockIdx.x * 16 + (tid >> 4);
    if (node >= n_nodes) return;
    int2 span = row_span[node];                     // A spans
    int s = span.x, cnt = span.y;
    const int4* Xv = (const int4*)XW;
    float a0=0,a1=0,a2=0,a3=0,a4=0,a5=0,a6=0,a7=0;
    int2 pl = make_int2(0, 0);
    if (lane < cnt) pl = pay[s + lane];
    for (int base = 0; base < cnt; base += 16) {
        int4 w[16];
        #pragma unroll
        for (int j = 0; j < 16; ++j) {
            int c = __shfl(pl.x, j, 16);            // pad lanes: c=0 (L1-hot row)
            w[j] = Xv[(size_t)((c << 4) | lane)];
        }
        int2 pln = make_int2(0, 0);
        if (base + 16 + lane < cnt) pln = pay[s + base + 16 + lane];
        #pragma unroll
        for (int j = 0; j < 16; ++j) {
            float v = __int_as_float(__shfl(pl.y, j, 16));  // pad lanes: v=0
            union { int4 i4; __half2 h[4]; } u;
            u.i4 = w[j];
            float2 f0 = __half22float2(u.h[0]);
            float2 f1 = __half22float2(u.h[1]);
            float2 f2 = __half22float2(u.h[2]);
            float2 f3 = __half22float2(u.h[3]);
            a0 += v * f0.x; a1 += v * f0.y; a2 += v * f1.x; a3 += v * f1.y;
            a4 += v * f2.x; a5 += v * f2.y; a6 += v * f3.x; a7 += v * f3.y;
        }
        pl = pln;
    }
    float4 lo, hi;
    lo.x = fmaxf(a0, 0.f); lo.y = fmaxf(a1, 0.f);
    lo.z = fmaxf(a2, 0.f); lo.w = fmaxf(a3, 0.f);
    hi.x = fmaxf(a4, 0.f); hi.y = fmaxf(a5, 0.f);
    hi.z = fmaxf(a6, 0.f); hi.w = fmaxf(a7, 0.f);
    float4* orow = (float4*)(out + (size_t)node * OUT_DIM);
    orow[2 * lane]     = lo;
    orow[2 * lane + 1] = hi;
}

extern "C" void kernel_launch(void* const* d_in, const int* in_sizes, int n_in,
                              void* d_out, int out_size, void* d_ws, size_t ws_size,
                              hipStream_t stream) {
    const int*   feat_rows = (const int*)d_in[0];
    const int*   feat_cols = (const int*)d_in[1];
    const float* feat_vals = (const float*)d_in[2];
    const int*   adj_rows  = (const int*)d_in[3];
    const int*   adj_cols  = (const int*)d_in[4];
    const float* adj_vals  = (const float*)d_in[5];
    const float* W         = (const float*)d_in[6];
    float*       out       = (float*)d_out;

    const int nnz_x   = in_sizes[0];
    const int nnz_a   = in_sizes[3];
    const int n_w     = in_sizes[6];          // 256*128
    const int n_nodes = out_size / OUT_DIM;
    const int ns      = (n_nodes + NPS - 1) / NPS;   // 391

    // ---- workspace layout (~56 MB) ----
    char* p = (char*)d_ws;
    __half* XW   = (__half*)p;  p += (size_t)n_nodes * OUT_DIM * sizeof(__half); // 25.6 MB
    __half* W16  = (__half*)p;  p += (size_t)n_w * sizeof(__half);               // 64 KB
    p = (char*)(((uintptr_t)p + 127) & ~(uintptr_t)127);
    int2* pay    = (int2*)p;    p += (size_t)2 * ns * CAP_S * sizeof(int2);      // 28.8 MB
    int2* row_span = (int2*)p;  p += (size_t)2 * n_nodes * sizeof(int2);         // 1.6 MB
    p = (char*)(((uintptr_t)p + 127) & ~(uintptr_t)127);
    int* cur     = (int*)p;     p += (size_t)2 * ns * CURSTR * sizeof(int);      // 100 KB

    (void)hipMemsetAsync(cur, 0, (size_t)2 * ns * CURSTR * sizeof(int), stream);

    wcast_kernel<<<(n_w + 255) / 256, 256, 0, stream>>>(W, W16, n_w);

    const int nCkA = (nnz_a + CHUNK1 - 1) / CHUNK1;
    const int nCkX = (nnz_x + CHUNK1 - 1) / CHUNK1;
    scatter1_kernel<<<nCkA + nCkX, SBLK1, 0, stream>>>(
        adj_rows, adj_cols, adj_vals, nnz_a, nCkA,
        feat_rows, feat_cols, feat_vals, nnz_x,
        cur, pay, ns);

    sort2x_kernel<<<ns, SBLK2, 0, stream>>>(cur, pay, row_span, ns, n_nodes);

    const int gnb64 = (n_nodes + 63) / 64;
    sortA_xw_kernel<<<ns + gnb64, SBLK2, 0, stream>>>(
        cur, pay, row_span, W16, XW, ns, n_nodes);

    const int gnb = (n_nodes + 15) / 16;
    gather_agg_kernel<<<gnb, GBLK, 0, stream>>>(row_span, pay, XW, out, n_nodes);
}